// Round 1
// 13248.608 us; speedup vs baseline: 1.9760x; 1.9760x over previous
//
#include <hip/hip_runtime.h>

#define SEQ_T 1024
#define HID   1024
#define EMB   512
#define VOC   512

typedef _Float16 f16;
typedef _Float16 half8 __attribute__((ext_vector_type(8)));
typedef float floatx4 __attribute__((ext_vector_type(4)));

__device__ __forceinline__ float tanh_fast(float x) {
  float e = __expf(2.0f * x);
  return 1.0f - 2.0f / (e + 1.0f);
}

// Cache-bypassing (coherence-point) load/store: data moves through the
// Infinity Cache directly, so no buffer_inv / buffer_wbl2 fences are needed
// for cross-XCD visibility.
__device__ __forceinline__ half8 ld_cc(const f16* p) {
  half8 v;
  asm volatile("global_load_dwordx4 %0, %1, off sc0 sc1"
               : "=v"(v) : "v"(p) : "memory");
  return v;
}
__device__ __forceinline__ void st_cc(f16* p, f16 x) {
  unsigned v = (unsigned)__builtin_bit_cast(unsigned short, x);
  asm volatile("global_store_short %0, %1, off sc0 sc1"
               :: "v"(p), "v"(v) : "memory");
}
#define VMCNT(n) asm volatile("s_waitcnt vmcnt(" #n ")" ::: "memory")

__global__ void cvt_f32_f16(const float* __restrict__ src, f16* __restrict__ dst, int n) {
  int i = blockIdx.x * 256 + threadIdx.x;
  if (i < n) dst[i] = (f16)src[i];
}

// X0[(t*128+b)][j] = sum_k emb[ids[b][t]][k] * wxh0[j][k] + b_h0[j]   (store f16)
__global__ __launch_bounds__(256) void phaseA(
    const int* __restrict__ ids, const f16* __restrict__ embh,
    const f16* __restrict__ wxh0h, const float* __restrict__ bh0,
    f16* __restrict__ X0)
{
  int bx = blockIdx.x;
  int mt = bx >> 4, nt = bx & 15;
  int wave = threadIdx.x >> 6, lane = threadIdx.x & 63;
  int m0 = mt * 64 + (wave & 1) * 32;
  int n0 = nt * 64 + (wave >> 1) * 32;
  int l15 = lane & 15, q = lane >> 4;

  int mA = m0 + l15, mB = mA + 16;
  const f16* a0p = embh + (size_t)ids[(mA & 127) * SEQ_T + (mA >> 7)] * EMB + q * 8;
  const f16* a1p = embh + (size_t)ids[(mB & 127) * SEQ_T + (mB >> 7)] * EMB + q * 8;
  const f16* b0p = wxh0h + (size_t)(n0 + l15) * EMB + q * 8;
  const f16* b1p = wxh0h + (size_t)(n0 + 16 + l15) * EMB + q * 8;

  floatx4 acc[2][2] = {};
  for (int k = 0; k < EMB; k += 32) {
    half8 a0 = *(const half8*)(a0p + k);
    half8 a1 = *(const half8*)(a1p + k);
    half8 b0 = *(const half8*)(b0p + k);
    half8 b1 = *(const half8*)(b1p + k);
    acc[0][0] = __builtin_amdgcn_mfma_f32_16x16x32_f16(a0, b0, acc[0][0], 0, 0, 0);
    acc[0][1] = __builtin_amdgcn_mfma_f32_16x16x32_f16(a0, b1, acc[0][1], 0, 0, 0);
    acc[1][0] = __builtin_amdgcn_mfma_f32_16x16x32_f16(a1, b0, acc[1][0], 0, 0, 0);
    acc[1][1] = __builtin_amdgcn_mfma_f32_16x16x32_f16(a1, b1, acc[1][1], 0, 0, 0);
  }
  for (int i = 0; i < 2; i++)
    for (int j = 0; j < 2; j++) {
      int col = n0 + j * 16 + l15;
      float bias = bh0[col];
      for (int e = 0; e < 4; e++) {
        int row = m0 + i * 16 + q * 4 + e;
        X0[(size_t)row * HID + col] = (f16)(acc[i][j][e] + bias);
      }
    }
}

__device__ __forceinline__ void spin_ge(unsigned* p, unsigned tgt) {
  while (__hip_atomic_load(p, __ATOMIC_RELAXED, __HIP_MEMORY_SCOPE_AGENT) < tgt)
    __builtin_amdgcn_s_sleep(1);
}

// Persistent recurrence kernel (256 WGs co-resident at 1 WG/CU).
// WGs 0..127 = A-phase (layer 0), 128..255 = B-phase (layer 1).
// Fenceless cross-XCD handshake: exchanged h-tiles move via sc0sc1
// write-through stores / cache-bypass loads (coherence point = IC), so
// release = vmcnt(0)+barrier+relaxed agent atomic add; acquire = relaxed
// spin + barrier. No buffer_inv / buffer_wbl2 per step.
__global__ __launch_bounds__(256, 1) void rnn_persist(
    const float* __restrict__ whh0, const float* __restrict__ wxh1,
    const float* __restrict__ whh1, const float* __restrict__ bh1,
    const f16* __restrict__ X0, f16* __restrict__ h0buf, f16* __restrict__ h1buf,
    f16* __restrict__ H1, unsigned* __restrict__ cnt)
{
  const int wg = blockIdx.x;
  const bool isB = wg >= 128;
  const int id = isB ? (wg - 128) : wg;
  const int r = id >> 4;           // row-block 0..7 (16 batch rows each)
  const int c = id & 15;           // col-block 0..15 (64 cols each)
  const int wave = threadIdx.x >> 6;
  const int lane = threadIdx.x & 63;
  const int l15 = lane & 15, q = lane >> 4;
  const int r0 = r * 16;
  const int n0 = c * 64 + wave * 16;
  const int col = n0 + l15;

  unsigned* cA = cnt + r * 64;          // cacheline-separated counters
  unsigned* cB = cnt + 512 + r * 64;

  if (!isB) {
    // ---- A phase: weights = Whh0[col][k], k=0..1023 -> 32 frags ----
    half8 wa[32];
    {
      const float* wr = whh0 + (size_t)col * HID + q * 8;
      #pragma unroll
      for (int i = 0; i < 32; i++) {
        const float* p = wr + i * 32;
        #pragma unroll
        for (int j = 0; j < 8; j++) wa[i][j] = (f16)p[j];
      }
    }
    for (int t = 0; t < SEQ_T; t++) {
      const f16* h0prev = h0buf + (size_t)(t & 1) * 131072;
      f16* h0next = h0buf + (size_t)((t + 1) & 1) * 131072;
      const f16* x0t = X0 + (size_t)t * 131072;
      // prefetch X0 (read-only, independent of sync) before the spin
      f16 xv[4];
      #pragma unroll
      for (int e = 0; e < 4; e++)
        xv[e] = x0t[(size_t)(r0 + q * 4 + e) * HID + col];
      if (threadIdx.x == 0) {
        spin_ge(cA, 16u * t);                    // A(t-1) row r complete
        if (t >= 2) spin_ge(cB, 16u * (t - 1));  // B(t-2) done reading buffer
      }
      __syncthreads();
      VMCNT(0);   // drain X0 prefetch so counted vmcnt below is exact
      const f16* ap = h0prev + (size_t)(r0 + l15) * HID + q * 8;
      half8 a0[16], a1[16];
      #pragma unroll
      for (int i = 0; i < 16; i++) a0[i] = ld_cc(ap + i * 32);
      #pragma unroll
      for (int i = 0; i < 16; i++) a1[i] = ld_cc(ap + (16 + i) * 32);
      floatx4 acc = {};
      VMCNT(16);                                 // batch-0 landed
      __builtin_amdgcn_sched_barrier(0);
      #pragma unroll
      for (int i = 0; i < 16; i++)
        acc = __builtin_amdgcn_mfma_f32_16x16x32_f16(a0[i], wa[i], acc, 0, 0, 0);
      VMCNT(0);                                  // batch-1 landed
      __builtin_amdgcn_sched_barrier(0);
      #pragma unroll
      for (int i = 0; i < 16; i++)
        acc = __builtin_amdgcn_mfma_f32_16x16x32_f16(a1[i], wa[16 + i], acc, 0, 0, 0);
      #pragma unroll
      for (int e = 0; e < 4; e++) {
        int row = r0 + q * 4 + e;
        float v = acc[e] + (float)xv[e];
        st_cc(h0next + (size_t)row * HID + col, (f16)tanh_fast(v));
      }
      VMCNT(0);   // store acks from coherence point (release data half)
      __syncthreads();
      if (threadIdx.x == 0)
        __hip_atomic_fetch_add(cA, 1u, __ATOMIC_RELAXED, __HIP_MEMORY_SCOPE_AGENT);
    }
  } else {
    // ---- B phase: weights = [Wxh1 | Whh1][col][k] -> 64 frags ----
    half8 wb[64];
    {
      const float* wr1 = wxh1 + (size_t)col * HID + q * 8;
      const float* wr2 = whh1 + (size_t)col * HID + q * 8;
      #pragma unroll
      for (int i = 0; i < 32; i++) {
        const float* p = wr1 + i * 32;
        #pragma unroll
        for (int j = 0; j < 8; j++) wb[i][j] = (f16)p[j];
      }
      #pragma unroll
      for (int i = 0; i < 32; i++) {
        const float* p = wr2 + i * 32;
        #pragma unroll
        for (int j = 0; j < 8; j++) wb[32 + i][j] = (f16)p[j];
      }
    }
    const float bias = bh1[col];
    for (int t = 0; t < SEQ_T; t++) {
      const f16* h1old = h1buf + (size_t)(t & 1) * 131072;
      f16* h1new = h1buf + (size_t)((t + 1) & 1) * 131072;
      const f16* h0cur = h0buf + (size_t)((t + 1) & 1) * 131072;  // written by A(t)
      if (threadIdx.x == 0) {
        spin_ge(cA, 16u * (t + 1));   // A(t) row r complete
        spin_ge(cB, 16u * t);         // B(t-1) row r complete
      }
      __syncthreads();
      VMCNT(0);   // nothing should be outstanding; make counted waits exact
      const f16* ap0 = h0cur + (size_t)(r0 + l15) * HID + q * 8;
      const f16* ap1 = h1old + (size_t)(r0 + l15) * HID + q * 8;
      half8 a0[16], a1[16];
      floatx4 acc = {};
      // h0cur contribution, software-pipelined in 2 batches of 16
      #pragma unroll
      for (int i = 0; i < 16; i++) a0[i] = ld_cc(ap0 + i * 32);
      #pragma unroll
      for (int i = 0; i < 16; i++) a1[i] = ld_cc(ap0 + (16 + i) * 32);
      VMCNT(16);
      __builtin_amdgcn_sched_barrier(0);
      #pragma unroll
      for (int i = 0; i < 16; i++)
        acc = __builtin_amdgcn_mfma_f32_16x16x32_f16(a0[i], wb[i], acc, 0, 0, 0);
      __builtin_amdgcn_sched_barrier(0);
      // reuse a0 regs for h1old batch-0; issue before waiting on a1
      #pragma unroll
      for (int i = 0; i < 16; i++) a0[i] = ld_cc(ap1 + i * 32);
      VMCNT(16);
      __builtin_amdgcn_sched_barrier(0);
      #pragma unroll
      for (int i = 0; i < 16; i++)
        acc = __builtin_amdgcn_mfma_f32_16x16x32_f16(a1[i], wb[16 + i], acc, 0, 0, 0);
      __builtin_amdgcn_sched_barrier(0);
      #pragma unroll
      for (int i = 0; i < 16; i++) a1[i] = ld_cc(ap1 + (16 + i) * 32);
      VMCNT(16);
      __builtin_amdgcn_sched_barrier(0);
      #pragma unroll
      for (int i = 0; i < 16; i++)
        acc = __builtin_amdgcn_mfma_f32_16x16x32_f16(a0[i], wb[32 + i], acc, 0, 0, 0);
      VMCNT(0);
      __builtin_amdgcn_sched_barrier(0);
      #pragma unroll
      for (int i = 0; i < 16; i++)
        acc = __builtin_amdgcn_mfma_f32_16x16x32_f16(a1[i], wb[48 + i], acc, 0, 0, 0);
      f16* h1t = H1 + (size_t)t * 131072;
      #pragma unroll
      for (int e = 0; e < 4; e++) {
        int row = r0 + q * 4 + e;
        f16 v = (f16)tanh_fast(acc[e] + bias);
        st_cc(h1new + (size_t)row * HID + col, v);   // exchanged: write-through
        h1t[(size_t)row * HID + col] = v;            // output: normal cached store
      }
      VMCNT(0);   // all stores (incl. H1) drained before release
      __syncthreads();
      if (threadIdx.x == 0)
        __hip_atomic_fetch_add(cB, 1u, __ATOMIC_RELAXED, __HIP_MEMORY_SCOPE_AGENT);
    }
  }
}

// logits[b][t][v] = sum_k H1[(t*128+b)][k]*why[v][k] + by[v]   (fp32 out)
__global__ __launch_bounds__(256) void logitsK(
    const f16* __restrict__ H1, const f16* __restrict__ whyh,
    const float* __restrict__ by, float* __restrict__ out)
{
  int bx = blockIdx.x;
  int mt = bx >> 3, nt = bx & 7;
  int wave = threadIdx.x >> 6, lane = threadIdx.x & 63;
  int m0 = mt * 64 + (wave & 1) * 32;
  int n0 = nt * 64 + (wave >> 1) * 32;
  int l15 = lane & 15, q = lane >> 4;

  const f16* a0p = H1 + (size_t)(m0 + l15) * HID + q * 8;
  const f16* a1p = H1 + (size_t)(m0 + 16 + l15) * HID + q * 8;
  const f16* b0p = whyh + (size_t)(n0 + l15) * HID + q * 8;
  const f16* b1p = whyh + (size_t)(n0 + 16 + l15) * HID + q * 8;

  floatx4 acc[2][2] = {};
  for (int k = 0; k < HID; k += 32) {
    half8 a0 = *(const half8*)(a0p + k);
    half8 a1 = *(const half8*)(a1p + k);
    half8 b0 = *(const half8*)(b0p + k);
    half8 b1 = *(const half8*)(b1p + k);
    acc[0][0] = __builtin_amdgcn_mfma_f32_16x16x32_f16(a0, b0, acc[0][0], 0, 0, 0);
    acc[0][1] = __builtin_amdgcn_mfma_f32_16x16x32_f16(a0, b1, acc[0][1], 0, 0, 0);
    acc[1][0] = __builtin_amdgcn_mfma_f32_16x16x32_f16(a1, b0, acc[1][0], 0, 0, 0);
    acc[1][1] = __builtin_amdgcn_mfma_f32_16x16x32_f16(a1, b1, acc[1][1], 0, 0, 0);
  }
  for (int i = 0; i < 2; i++)
    for (int j = 0; j < 2; j++) {
      int col = n0 + j * 16 + l15;
      float bias = by[col];
      for (int e = 0; e < 4; e++) {
        int row = m0 + i * 16 + q * 4 + e;   // row = t*128 + b
        int t = row >> 7, b = row & 127;
        out[((size_t)b * SEQ_T + t) * VOC + col] = acc[i][j][e] + bias;
      }
    }
}

__global__ void finals(const f16* __restrict__ h0, const f16* __restrict__ h1,
                       float* __restrict__ out) {
  int i = blockIdx.x * 256 + threadIdx.x;  // 131072 threads
  out[(size_t)67108864 + i] = (float)h0[i];
  out[(size_t)67108864 + 131072 + i] = (float)h1[i];
}

extern "C" void kernel_launch(void* const* d_in, const int* in_sizes, int n_in,
                              void* d_out, int out_size, void* d_ws, size_t ws_size,
                              hipStream_t stream) {
  const int*   ids  = (const int*)d_in[0];
  const float* emb  = (const float*)d_in[1];
  const float* wxh0 = (const float*)d_in[2];
  const float* whh0 = (const float*)d_in[3];
  const float* bh0  = (const float*)d_in[4];
  const float* wxh1 = (const float*)d_in[5];
  const float* whh1 = (const float*)d_in[6];
  const float* bh1  = (const float*)d_in[7];
  const float* why  = (const float*)d_in[8];
  const float* by   = (const float*)d_in[9];
  float* out = (float*)d_out;

  char* ws = (char*)d_ws;
  f16* embh   = (f16*)(ws + 0);           // 512*512*2   = 524288
  f16* wxh0h  = (f16*)(ws + 524288);      // 1024*512*2  = 1048576
  f16* whyh   = (f16*)(ws + 1572864);     // 512*1024*2  = 1048576
  f16* h0buf  = (f16*)(ws + 2621440);     // 2 x 262144B = 524288
  f16* h1buf  = (f16*)(ws + 3145728);     // 524288
  unsigned* cnt = (unsigned*)(ws + 3670016);  // 4096
  f16* X0     = (f16*)(ws + 4194304);     // 268435456
  f16* H1     = (f16*)(ws + 272629760);   // 268435456   total ~528 MB

  cvt_f32_f16<<<1024, 256, 0, stream>>>(emb,  embh,  262144);
  cvt_f32_f16<<<2048, 256, 0, stream>>>(wxh0, wxh0h, 524288);
  cvt_f32_f16<<<2048, 256, 0, stream>>>(why,  whyh,  524288);
  hipMemsetAsync(ws + 2621440, 0, 1052672, stream);  // h0buf + h1buf + cnt

  phaseA<<<32768, 256, 0, stream>>>(ids, embh, wxh0h, bh0, X0);

  rnn_persist<<<256, 256, 0, stream>>>(whh0, wxh1, whh1, bh1,
                                       X0, h0buf, h1buf, H1, cnt);

  logitsK<<<16384, 256, 0, stream>>>(H1, whyh, by, out);
  finals<<<512, 256, 0, stream>>>(h0buf, h1buf, out);
}

// Round 2
// 10850.550 us; speedup vs baseline: 2.4127x; 1.2210x over previous
//
#include <hip/hip_runtime.h>

#define SEQ_T 1024
#define HID   1024
#define EMB   512
#define VOC   512

typedef _Float16 f16;
typedef _Float16 half8 __attribute__((ext_vector_type(8)));
typedef float floatx4 __attribute__((ext_vector_type(4)));

__device__ __forceinline__ float tanh_fast(float x) {
  float e = __expf(2.0f * x);
  return 1.0f - 2.0f / (e + 1.0f);
}

// Cache-bypassing (coherence-point) load/store: data moves through the
// Infinity Cache directly, so no buffer_inv / buffer_wbl2 fences are needed
// for cross-XCD visibility.
__device__ __forceinline__ half8 ld_cc(const f16* p) {
  half8 v;
  asm volatile("global_load_dwordx4 %0, %1, off sc0 sc1"
               : "=v"(v) : "v"(p) : "memory");
  return v;
}
__device__ __forceinline__ void st_cc(f16* p, f16 x) {
  unsigned v = (unsigned)__builtin_bit_cast(unsigned short, x);
  asm volatile("global_store_short %0, %1, off sc0 sc1"
               :: "v"(p), "v"(v) : "memory");
}
#define VMCNT(n) asm volatile("s_waitcnt vmcnt(" #n ")" ::: "memory")

__global__ void cvt_f32_f16(const float* __restrict__ src, f16* __restrict__ dst, int n) {
  int i = blockIdx.x * 256 + threadIdx.x;
  if (i < n) dst[i] = (f16)src[i];
}

// X0[(t*128+b)][j] = sum_k emb[ids[b][t]][k] * wxh0[j][k] + b_h0[j]   (store f16)
__global__ __launch_bounds__(256) void phaseA(
    const int* __restrict__ ids, const f16* __restrict__ embh,
    const f16* __restrict__ wxh0h, const float* __restrict__ bh0,
    f16* __restrict__ X0)
{
  int bx = blockIdx.x;
  int mt = bx >> 4, nt = bx & 15;
  int wave = threadIdx.x >> 6, lane = threadIdx.x & 63;
  int m0 = mt * 64 + (wave & 1) * 32;
  int n0 = nt * 64 + (wave >> 1) * 32;
  int l15 = lane & 15, q = lane >> 4;

  int mA = m0 + l15, mB = mA + 16;
  const f16* a0p = embh + (size_t)ids[(mA & 127) * SEQ_T + (mA >> 7)] * EMB + q * 8;
  const f16* a1p = embh + (size_t)ids[(mB & 127) * SEQ_T + (mB >> 7)] * EMB + q * 8;
  const f16* b0p = wxh0h + (size_t)(n0 + l15) * EMB + q * 8;
  const f16* b1p = wxh0h + (size_t)(n0 + 16 + l15) * EMB + q * 8;

  floatx4 acc[2][2] = {};
  for (int k = 0; k < EMB; k += 32) {
    half8 a0 = *(const half8*)(a0p + k);
    half8 a1 = *(const half8*)(a1p + k);
    half8 b0 = *(const half8*)(b0p + k);
    half8 b1 = *(const half8*)(b1p + k);
    acc[0][0] = __builtin_amdgcn_mfma_f32_16x16x32_f16(a0, b0, acc[0][0], 0, 0, 0);
    acc[0][1] = __builtin_amdgcn_mfma_f32_16x16x32_f16(a0, b1, acc[0][1], 0, 0, 0);
    acc[1][0] = __builtin_amdgcn_mfma_f32_16x16x32_f16(a1, b0, acc[1][0], 0, 0, 0);
    acc[1][1] = __builtin_amdgcn_mfma_f32_16x16x32_f16(a1, b1, acc[1][1], 0, 0, 0);
  }
  for (int i = 0; i < 2; i++)
    for (int j = 0; j < 2; j++) {
      int col = n0 + j * 16 + l15;
      float bias = bh0[col];
      for (int e = 0; e < 4; e++) {
        int row = m0 + i * 16 + q * 4 + e;
        X0[(size_t)row * HID + col] = (f16)(acc[i][j][e] + bias);
      }
    }
}

__device__ __forceinline__ void spin_ge(unsigned* p, unsigned tgt) {
  while (__hip_atomic_load(p, __ATOMIC_RELAXED, __HIP_MEMORY_SCOPE_AGENT) < tgt)
    __builtin_amdgcn_s_sleep(1);
}

// Persistent recurrence kernel (256 WGs co-resident at 1 WG/CU).
// WGs 0..127 = A-phase (layer 0), 128..255 = B-phase (layer 1).
// Fenceless cross-XCD handshake via sc0sc1 write-through stores /
// cache-bypass loads (coherence point = IC).
// This round:
//  - ALL threads spin (no thread0+__syncthreads detect hop); per-WAVE
//    release: each wave's lane0 posts +1 after its own vmcnt(0) store
//    drain. Counter threshold = 64 per row per step (16 WGs x 4 waves).
//  - Cooperative LDS staging of exchanged h-tiles: each wave ld_cc's 8
//    fragments, ds_writes, one barrier, all waves ds_read the full tile.
//    Cuts sc0sc1 IC read traffic 4x (48 -> 12 MB/step).
//    A double-buffers 2x32KB (no trailing barrier needed);
//    B single-buffers 64KB (h0|h1) + trailing barrier AFTER the posts.
__global__ __launch_bounds__(256, 1) void rnn_persist(
    const float* __restrict__ whh0, const float* __restrict__ wxh1,
    const float* __restrict__ whh1, const float* __restrict__ bh1,
    const f16* __restrict__ X0, f16* __restrict__ h0buf, f16* __restrict__ h1buf,
    f16* __restrict__ H1, unsigned* __restrict__ cnt)
{
  __shared__ half8 lds[4096];   // 64 KB: A: 2 x 2048 frag-slots; B: h0[0..2048) h1[2048..4096)

  const int wg = blockIdx.x;
  const bool isB = wg >= 128;
  const int id = isB ? (wg - 128) : wg;
  const int r = id >> 4;           // row-block 0..7 (16 batch rows each)
  const int c = id & 15;           // col-block 0..15 (64 cols each)
  const int wave = threadIdx.x >> 6;
  const int lane = threadIdx.x & 63;
  const int l15 = lane & 15, q = lane >> 4;
  const int r0 = r * 16;
  const int n0 = c * 64 + wave * 16;
  const int col = n0 + l15;

  unsigned* cA = cnt + r * 64;          // cacheline-separated counters
  unsigned* cB = cnt + 512 + r * 64;

  if (!isB) {
    // ---- A phase: weights = Whh0[col][k], k=0..1023 -> 32 frags ----
    half8 wa[32];
    {
      const float* wr = whh0 + (size_t)col * HID + q * 8;
      #pragma unroll
      for (int i = 0; i < 32; i++) {
        const float* p = wr + i * 32;
        #pragma unroll
        for (int j = 0; j < 8; j++) wa[i][j] = (f16)p[j];
      }
    }
    for (int t = 0; t < SEQ_T; t++) {
      const f16* h0prev = h0buf + (size_t)(t & 1) * 131072;
      f16* h0next = h0buf + (size_t)((t + 1) & 1) * 131072;
      const f16* x0t = X0 + (size_t)t * 131072;
      half8* ldsbuf = lds + (size_t)(t & 1) * 2048;
      // prefetch X0 (read-only, independent of sync) before the spin
      f16 xv[4];
      #pragma unroll
      for (int e = 0; e < 4; e++)
        xv[e] = x0t[(size_t)(r0 + q * 4 + e) * HID + col];
      // all-thread spin (same-address wave load = 1 request/wave)
      spin_ge(cA, 64u * t);                     // A(t-1) row r complete
      if (t >= 2) spin_ge(cB, 64u * (t - 1));   // B(t-2) done reading buffer
      // cooperative stage: this wave loads frags 8w..8w+7
      const f16* ap = h0prev + (size_t)(r0 + l15) * HID + q * 8;
      half8 v[8];
      #pragma unroll
      for (int i = 0; i < 8; i++) v[i] = ld_cc(ap + (8 * wave + i) * 32);
      VMCNT(0);
      #pragma unroll
      for (int i = 0; i < 8; i++) ldsbuf[(8 * wave + i) * 64 + lane] = v[i];
      __syncthreads();
      floatx4 acc = {};
      #pragma unroll
      for (int i = 0; i < 32; i++) {
        half8 a = ldsbuf[i * 64 + lane];
        acc = __builtin_amdgcn_mfma_f32_16x16x32_f16(a, wa[i], acc, 0, 0, 0);
      }
      #pragma unroll
      for (int e = 0; e < 4; e++) {
        int row = r0 + q * 4 + e;
        float vv = acc[e] + (float)xv[e];
        st_cc(h0next + (size_t)row * HID + col, (f16)tanh_fast(vv));
      }
      VMCNT(0);   // this wave's store acks from coherence point
      if (lane == 0)
        __hip_atomic_fetch_add(cA, 1u, __ATOMIC_RELAXED, __HIP_MEMORY_SCOPE_AGENT);
      // no trailing barrier: LDS double-buffered, a wave can be at most
      // 1 step ahead of a wave it shares the barrier with.
    }
  } else {
    // ---- B phase: weights = [Wxh1 | Whh1][col][k] -> 64 frags ----
    half8 wb[64];
    {
      const float* wr1 = wxh1 + (size_t)col * HID + q * 8;
      const float* wr2 = whh1 + (size_t)col * HID + q * 8;
      #pragma unroll
      for (int i = 0; i < 32; i++) {
        const float* p = wr1 + i * 32;
        #pragma unroll
        for (int j = 0; j < 8; j++) wb[i][j] = (f16)p[j];
      }
      #pragma unroll
      for (int i = 0; i < 32; i++) {
        const float* p = wr2 + i * 32;
        #pragma unroll
        for (int j = 0; j < 8; j++) wb[32 + i][j] = (f16)p[j];
      }
    }
    const float bias = bh1[col];
    for (int t = 0; t < SEQ_T; t++) {
      const f16* h1old = h1buf + (size_t)(t & 1) * 131072;
      f16* h1new = h1buf + (size_t)((t + 1) & 1) * 131072;
      const f16* h0cur = h0buf + (size_t)((t + 1) & 1) * 131072;  // written by A(t)
      // all-thread spin
      spin_ge(cA, 64u * (t + 1));   // A(t) row r complete
      spin_ge(cB, 64u * t);         // B(t-1) row r complete
      // cooperative stage: this wave loads h0 frags 8w..8w+7 and h1 frags 8w..8w+7
      const f16* ap0 = h0cur + (size_t)(r0 + l15) * HID + q * 8;
      const f16* ap1 = h1old + (size_t)(r0 + l15) * HID + q * 8;
      half8 v0[8], v1[8];
      #pragma unroll
      for (int i = 0; i < 8; i++) v0[i] = ld_cc(ap0 + (8 * wave + i) * 32);
      #pragma unroll
      for (int i = 0; i < 8; i++) v1[i] = ld_cc(ap1 + (8 * wave + i) * 32);
      VMCNT(0);
      #pragma unroll
      for (int i = 0; i < 8; i++) lds[(8 * wave + i) * 64 + lane] = v0[i];
      #pragma unroll
      for (int i = 0; i < 8; i++) lds[2048 + (8 * wave + i) * 64 + lane] = v1[i];
      __syncthreads();
      floatx4 acc = {};
      #pragma unroll
      for (int i = 0; i < 32; i++) {
        half8 a = lds[i * 64 + lane];
        acc = __builtin_amdgcn_mfma_f32_16x16x32_f16(a, wb[i], acc, 0, 0, 0);
      }
      #pragma unroll
      for (int i = 0; i < 32; i++) {
        half8 a = lds[2048 + i * 64 + lane];
        acc = __builtin_amdgcn_mfma_f32_16x16x32_f16(a, wb[32 + i], acc, 0, 0, 0);
      }
      f16* h1t = H1 + (size_t)t * 131072;
      #pragma unroll
      for (int e = 0; e < 4; e++) {
        int row = r0 + q * 4 + e;
        f16 v = (f16)tanh_fast(acc[e] + bias);
        st_cc(h1new + (size_t)row * HID + col, v);   // exchanged: write-through
        h1t[(size_t)row * HID + col] = v;            // output: normal cached store
      }
      VMCNT(0);   // this wave's stores (incl. H1) drained
      if (lane == 0)
        __hip_atomic_fetch_add(cB, 1u, __ATOMIC_RELAXED, __HIP_MEMORY_SCOPE_AGENT);
      __syncthreads();   // LDS single-buffered: protect reuse (off inter-WG path)
    }
  }
}

// logits[b][t][v] = sum_k H1[(t*128+b)][k]*why[v][k] + by[v]   (fp32 out)
__global__ __launch_bounds__(256) void logitsK(
    const f16* __restrict__ H1, const f16* __restrict__ whyh,
    const float* __restrict__ by, float* __restrict__ out)
{
  int bx = blockIdx.x;
  int mt = bx >> 3, nt = bx & 7;
  int wave = threadIdx.x >> 6, lane = threadIdx.x & 63;
  int m0 = mt * 64 + (wave & 1) * 32;
  int n0 = nt * 64 + (wave >> 1) * 32;
  int l15 = lane & 15, q = lane >> 4;

  const f16* a0p = H1 + (size_t)(m0 + l15) * HID + q * 8;
  const f16* a1p = H1 + (size_t)(m0 + 16 + l15) * HID + q * 8;
  const f16* b0p = whyh + (size_t)(n0 + l15) * HID + q * 8;
  const f16* b1p = whyh + (size_t)(n0 + 16 + l15) * HID + q * 8;

  floatx4 acc[2][2] = {};
  for (int k = 0; k < HID; k += 32) {
    half8 a0 = *(const half8*)(a0p + k);
    half8 a1 = *(const half8*)(a1p + k);
    half8 b0 = *(const half8*)(b0p + k);
    half8 b1 = *(const half8*)(b1p + k);
    acc[0][0] = __builtin_amdgcn_mfma_f32_16x16x32_f16(a0, b0, acc[0][0], 0, 0, 0);
    acc[0][1] = __builtin_amdgcn_mfma_f32_16x16x32_f16(a0, b1, acc[0][1], 0, 0, 0);
    acc[1][0] = __builtin_amdgcn_mfma_f32_16x16x32_f16(a1, b0, acc[1][0], 0, 0, 0);
    acc[1][1] = __builtin_amdgcn_mfma_f32_16x16x32_f16(a1, b1, acc[1][1], 0, 0, 0);
  }
  for (int i = 0; i < 2; i++)
    for (int j = 0; j < 2; j++) {
      int col = n0 + j * 16 + l15;
      float bias = by[col];
      for (int e = 0; e < 4; e++) {
        int row = m0 + i * 16 + q * 4 + e;   // row = t*128 + b
        int t = row >> 7, b = row & 127;
        out[((size_t)b * SEQ_T + t) * VOC + col] = acc[i][j][e] + bias;
      }
    }
}

__global__ void finals(const f16* __restrict__ h0, const f16* __restrict__ h1,
                       float* __restrict__ out) {
  int i = blockIdx.x * 256 + threadIdx.x;  // 131072 threads
  out[(size_t)67108864 + i] = (float)h0[i];
  out[(size_t)67108864 + 131072 + i] = (float)h1[i];
}

extern "C" void kernel_launch(void* const* d_in, const int* in_sizes, int n_in,
                              void* d_out, int out_size, void* d_ws, size_t ws_size,
                              hipStream_t stream) {
  const int*   ids  = (const int*)d_in[0];
  const float* emb  = (const float*)d_in[1];
  const float* wxh0 = (const float*)d_in[2];
  const float* whh0 = (const float*)d_in[3];
  const float* bh0  = (const float*)d_in[4];
  const float* wxh1 = (const float*)d_in[5];
  const float* whh1 = (const float*)d_in[6];
  const float* bh1  = (const float*)d_in[7];
  const float* why  = (const float*)d_in[8];
  const float* by   = (const float*)d_in[9];
  float* out = (float*)d_out;

  char* ws = (char*)d_ws;
  f16* embh   = (f16*)(ws + 0);           // 512*512*2   = 524288
  f16* wxh0h  = (f16*)(ws + 524288);      // 1024*512*2  = 1048576
  f16* whyh   = (f16*)(ws + 1572864);     // 512*1024*2  = 1048576
  f16* h0buf  = (f16*)(ws + 2621440);     // 2 x 262144B = 524288
  f16* h1buf  = (f16*)(ws + 3145728);     // 524288
  unsigned* cnt = (unsigned*)(ws + 3670016);  // 4096
  f16* X0     = (f16*)(ws + 4194304);     // 268435456
  f16* H1     = (f16*)(ws + 272629760);   // 268435456   total ~528 MB

  cvt_f32_f16<<<1024, 256, 0, stream>>>(emb,  embh,  262144);
  cvt_f32_f16<<<2048, 256, 0, stream>>>(wxh0, wxh0h, 524288);
  cvt_f32_f16<<<2048, 256, 0, stream>>>(why,  whyh,  524288);
  hipMemsetAsync(ws + 2621440, 0, 1052672, stream);  // h0buf + h1buf + cnt

  phaseA<<<32768, 256, 0, stream>>>(ids, embh, wxh0h, bh0, X0);

  rnn_persist<<<256, 256, 0, stream>>>(whh0, wxh1, whh1, bh1,
                                       X0, h0buf, h1buf, H1, cnt);

  logitsK<<<16384, 256, 0, stream>>>(H1, whyh, by, out);
  finals<<<512, 256, 0, stream>>>(h0buf, h1buf, out);
}

// Round 3
// 9961.526 us; speedup vs baseline: 2.6280x; 1.0892x over previous
//
#include <hip/hip_runtime.h>

#define SEQ_T 1024
#define HID   1024
#define EMB   512
#define VOC   512

typedef _Float16 f16;
typedef _Float16 half8 __attribute__((ext_vector_type(8)));
typedef float floatx4 __attribute__((ext_vector_type(4)));

__device__ __forceinline__ float tanh_fast(float x) {
  float e = __expf(2.0f * x);
  return 1.0f - 2.0f / (e + 1.0f);
}

// Cache-bypassing (coherence-point) load/store: data moves through the
// Infinity Cache directly, so no buffer_inv / buffer_wbl2 fences are needed
// for cross-XCD visibility.
__device__ __forceinline__ half8 ld_cc(const f16* p) {
  half8 v;
  asm volatile("global_load_dwordx4 %0, %1, off sc0 sc1"
               : "=v"(v) : "v"(p) : "memory");
  return v;
}
__device__ __forceinline__ void st_cc(f16* p, f16 x) {
  unsigned v = (unsigned)__builtin_bit_cast(unsigned short, x);
  asm volatile("global_store_short %0, %1, off sc0 sc1"
               :: "v"(p), "v"(v) : "memory");
}
#define VMCNT(n) asm volatile("s_waitcnt vmcnt(" #n ")" ::: "memory")

__global__ void cvt_f32_f16(const float* __restrict__ src, f16* __restrict__ dst, int n) {
  int i = blockIdx.x * 256 + threadIdx.x;
  if (i < n) dst[i] = (f16)src[i];
}

// X0[(t*128+b)][j] = sum_k emb[ids[b][t]][k] * wxh0[j][k] + b_h0[j]   (store f16)
__global__ __launch_bounds__(256) void phaseA(
    const int* __restrict__ ids, const f16* __restrict__ embh,
    const f16* __restrict__ wxh0h, const float* __restrict__ bh0,
    f16* __restrict__ X0)
{
  int bx = blockIdx.x;
  int mt = bx >> 4, nt = bx & 15;
  int wave = threadIdx.x >> 6, lane = threadIdx.x & 63;
  int m0 = mt * 64 + (wave & 1) * 32;
  int n0 = nt * 64 + (wave >> 1) * 32;
  int l15 = lane & 15, q = lane >> 4;

  int mA = m0 + l15, mB = mA + 16;
  const f16* a0p = embh + (size_t)ids[(mA & 127) * SEQ_T + (mA >> 7)] * EMB + q * 8;
  const f16* a1p = embh + (size_t)ids[(mB & 127) * SEQ_T + (mB >> 7)] * EMB + q * 8;
  const f16* b0p = wxh0h + (size_t)(n0 + l15) * EMB + q * 8;
  const f16* b1p = wxh0h + (size_t)(n0 + 16 + l15) * EMB + q * 8;

  floatx4 acc[2][2] = {};
  for (int k = 0; k < EMB; k += 32) {
    half8 a0 = *(const half8*)(a0p + k);
    half8 a1 = *(const half8*)(a1p + k);
    half8 b0 = *(const half8*)(b0p + k);
    half8 b1 = *(const half8*)(b1p + k);
    acc[0][0] = __builtin_amdgcn_mfma_f32_16x16x32_f16(a0, b0, acc[0][0], 0, 0, 0);
    acc[0][1] = __builtin_amdgcn_mfma_f32_16x16x32_f16(a0, b1, acc[0][1], 0, 0, 0);
    acc[1][0] = __builtin_amdgcn_mfma_f32_16x16x32_f16(a1, b0, acc[1][0], 0, 0, 0);
    acc[1][1] = __builtin_amdgcn_mfma_f32_16x16x32_f16(a1, b1, acc[1][1], 0, 0, 0);
  }
  for (int i = 0; i < 2; i++)
    for (int j = 0; j < 2; j++) {
      int col = n0 + j * 16 + l15;
      float bias = bh0[col];
      for (int e = 0; e < 4; e++) {
        int row = m0 + i * 16 + q * 4 + e;
        X0[(size_t)row * HID + col] = (f16)(acc[i][j][e] + bias);
      }
    }
}

__device__ __forceinline__ void spin_ge(unsigned* p, unsigned tgt) {
  while (__hip_atomic_load(p, __ATOMIC_RELAXED, __HIP_MEMORY_SCOPE_AGENT) < tgt)
    __builtin_amdgcn_s_sleep(1);
}

// Persistent recurrence kernel: 128 WGs (8 row-blocks x 16 col-blocks),
// each WG computes BOTH layers for its (r,c) tile; layer 1 lags one step.
// Per iteration t (0..1024):
//   gather {h0(t-1), h1(t-2)} row-slices into LDS  [ONE cross-WG hop]
//   A-part (t<1024): h0(t) = tanh(X0(t) + h0(t-1)@Whh0^T)  -> post cA
//   B-part (t>=1):   h1(t-1) = tanh(h0(t-1)@Wxh1^T + h1(t-2)@Whh1^T + b)
//                    (inputs read from LDS -> no second cross-WG hop) -> post cB
// Fenceless sc0sc1 write-through handshake as before. H1 cached stores are
// issued AFTER the cB post so their HBM ack is off the critical drain.
// 96 weight frags/wave (~384 regs) live in the unified VGPR/AGPR file
// (1 wave/SIMD -> 512 regs/wave).
__global__ __launch_bounds__(256, 1) void rnn_persist(
    const float* __restrict__ whh0, const float* __restrict__ wxh1,
    const float* __restrict__ whh1, const float* __restrict__ bh1,
    const f16* __restrict__ X0, f16* __restrict__ h0buf, f16* __restrict__ h1buf,
    f16* __restrict__ H1, unsigned* __restrict__ cnt)
{
  __shared__ half8 lds[4096];   // [0,2048): h0(t-1) stage; [2048,4096): h1(t-2) stage

  const int wg = blockIdx.x;       // 0..127
  const int r = wg >> 4;           // row-block 0..7 (16 batch rows each)
  const int c = wg & 15;           // col-block 0..15 (64 cols each)
  const int wave = threadIdx.x >> 6;
  const int lane = threadIdx.x & 63;
  const int l15 = lane & 15, q = lane >> 4;
  const int r0 = r * 16;
  const int col = c * 64 + wave * 16 + l15;

  unsigned* cA = cnt + r * 64;          // cacheline-separated counters
  unsigned* cB = cnt + 512 + r * 64;

  // ---- weights: Whh0 | Wxh1 | Whh1 for this col, 96 frags ----
  half8 wa[32], wbx[32], wbh[32];
  {
    const float* w0 = whh0 + (size_t)col * HID + q * 8;
    const float* w1 = wxh1 + (size_t)col * HID + q * 8;
    const float* w2 = whh1 + (size_t)col * HID + q * 8;
    #pragma unroll
    for (int i = 0; i < 32; i++) {
      const float* p0 = w0 + i * 32;
      const float* p1 = w1 + i * 32;
      const float* p2 = w2 + i * 32;
      #pragma unroll
      for (int j = 0; j < 8; j++) {
        wa[i][j]  = (f16)p0[j];
        wbx[i][j] = (f16)p1[j];
        wbh[i][j] = (f16)p2[j];
      }
    }
  }
  const float bias1 = bh1[col];

  for (int t = 0; t <= SEQ_T; t++) {
    // h0(s) lives in h0buf[(s+1)&1]; h1(s) lives in h1buf[(s+1)&1]
    const f16* h0prev  = h0buf + (size_t)(t & 1) * 131072;        // h0(t-1)
    f16*       h0next  = h0buf + (size_t)((t + 1) & 1) * 131072;  // h0(t)
    const f16* h1prev2 = h1buf + (size_t)((t + 1) & 1) * 131072;  // h1(t-2)
    f16*       h1new   = h1buf + (size_t)(t & 1) * 131072;        // h1(t-1)

    // X0 prefetch (independent of sync) before the spin
    f16 xv[4];
    if (t < SEQ_T) {
      const f16* x0t = X0 + (size_t)t * 131072;
      #pragma unroll
      for (int e = 0; e < 4; e++)
        xv[e] = x0t[(size_t)(r0 + q * 4 + e) * HID + col];
    }

    // detect: all-thread spin (same-address wave load = 1 request/wave)
    if (t >= 1) spin_ge(cA, 64u * t);         // A(t-1) row r complete (incl. gathers)
    if (t >= 2) spin_ge(cB, 64u * (t - 1));   // B-part of iter t-1 complete

    // gather: this wave loads h0 frags 8w..8w+7 and h1 frags 8w..8w+7
    const f16* ap0 = h0prev  + (size_t)(r0 + l15) * HID + q * 8;
    const f16* ap1 = h1prev2 + (size_t)(r0 + l15) * HID + q * 8;
    half8 v0[8], v1[8];
    #pragma unroll
    for (int i = 0; i < 8; i++) v0[i] = ld_cc(ap0 + (8 * wave + i) * 32);
    #pragma unroll
    for (int i = 0; i < 8; i++) v1[i] = ld_cc(ap1 + (8 * wave + i) * 32);
    VMCNT(8);     // v0 batch (and xv prefetch) landed
    #pragma unroll
    for (int i = 0; i < 8; i++) lds[(8 * wave + i) * 64 + lane] = v0[i];
    VMCNT(0);     // v1 batch landed
    #pragma unroll
    for (int i = 0; i < 8; i++) lds[2048 + (8 * wave + i) * 64 + lane] = v1[i];
    __syncthreads();

    // ---- A-part: h0(t) = tanh(X0(t) + h0(t-1) @ Whh0^T) ----
    if (t < SEQ_T) {
      floatx4 a0 = {}, a1 = {};
      #pragma unroll
      for (int i = 0; i < 16; i++) {
        half8 f0 = lds[i * 64 + lane];
        half8 f1 = lds[(16 + i) * 64 + lane];
        a0 = __builtin_amdgcn_mfma_f32_16x16x32_f16(f0, wa[i],      a0, 0, 0, 0);
        a1 = __builtin_amdgcn_mfma_f32_16x16x32_f16(f1, wa[16 + i], a1, 0, 0, 0);
      }
      #pragma unroll
      for (int e = 0; e < 4; e++) {
        int row = r0 + q * 4 + e;
        float vv = a0[e] + a1[e] + (float)xv[e];
        st_cc(h0next + (size_t)row * HID + col, (f16)tanh_fast(vv));
      }
      VMCNT(0);   // h0 store acks from coherence point
      if (lane == 0)
        __hip_atomic_fetch_add(cA, 1u, __ATOMIC_RELAXED, __HIP_MEMORY_SCOPE_AGENT);
    }

    // ---- B-part: h1(t-1) = tanh(h0(t-1)@Wxh1^T + h1(t-2)@Whh1^T + b1) ----
    // Both inputs are already in LDS: no cross-WG hop.
    if (t >= 1) {
      floatx4 b0 = {}, b1 = {};
      #pragma unroll
      for (int i = 0; i < 32; i++) {
        half8 f0 = lds[i * 64 + lane];          // h0(t-1)
        half8 f1 = lds[2048 + i * 64 + lane];   // h1(t-2)
        b0 = __builtin_amdgcn_mfma_f32_16x16x32_f16(f0, wbx[i], b0, 0, 0, 0);
        b1 = __builtin_amdgcn_mfma_f32_16x16x32_f16(f1, wbh[i], b1, 0, 0, 0);
      }
      f16 hv[4];
      #pragma unroll
      for (int e = 0; e < 4; e++) {
        int row = r0 + q * 4 + e;
        hv[e] = (f16)tanh_fast(b0[e] + b1[e] + bias1);
        st_cc(h1new + (size_t)row * HID + col, hv[e]);
      }
      VMCNT(0);   // h1 write-through acks (H1 stores NOT yet issued)
      if (lane == 0)
        __hip_atomic_fetch_add(cB, 1u, __ATOMIC_RELAXED, __HIP_MEMORY_SCOPE_AGENT);
      // output slice t-1: cached stores issued AFTER the post (off critical path)
      f16* h1t = H1 + (size_t)(t - 1) * 131072;
      #pragma unroll
      for (int e = 0; e < 4; e++) {
        int row = r0 + q * 4 + e;
        h1t[(size_t)row * HID + col] = hv[e];
      }
    }
    __syncthreads();   // protect LDS reuse before next iteration's gather-writes
  }
}

// logits[b][t][v] = sum_k H1[(t*128+b)][k]*why[v][k] + by[v]   (fp32 out)
__global__ __launch_bounds__(256) void logitsK(
    const f16* __restrict__ H1, const f16* __restrict__ whyh,
    const float* __restrict__ by, float* __restrict__ out)
{
  int bx = blockIdx.x;
  int mt = bx >> 3, nt = bx & 7;
  int wave = threadIdx.x >> 6, lane = threadIdx.x & 63;
  int m0 = mt * 64 + (wave & 1) * 32;
  int n0 = nt * 64 + (wave >> 1) * 32;
  int l15 = lane & 15, q = lane >> 4;

  const f16* a0p = H1 + (size_t)(m0 + l15) * HID + q * 8;
  const f16* a1p = H1 + (size_t)(m0 + 16 + l15) * HID + q * 8;
  const f16* b0p = whyh + (size_t)(n0 + l15) * HID + q * 8;
  const f16* b1p = whyh + (size_t)(n0 + 16 + l15) * HID + q * 8;

  floatx4 acc[2][2] = {};
  for (int k = 0; k < HID; k += 32) {
    half8 a0 = *(const half8*)(a0p + k);
    half8 a1 = *(const half8*)(a1p + k);
    half8 b0 = *(const half8*)(b0p + k);
    half8 b1 = *(const half8*)(b1p + k);
    acc[0][0] = __builtin_amdgcn_mfma_f32_16x16x32_f16(a0, b0, acc[0][0], 0, 0, 0);
    acc[0][1] = __builtin_amdgcn_mfma_f32_16x16x32_f16(a0, b1, acc[0][1], 0, 0, 0);
    acc[1][0] = __builtin_amdgcn_mfma_f32_16x16x32_f16(a1, b0, acc[1][0], 0, 0, 0);
    acc[1][1] = __builtin_amdgcn_mfma_f32_16x16x32_f16(a1, b1, acc[1][1], 0, 0, 0);
  }
  for (int i = 0; i < 2; i++)
    for (int j = 0; j < 2; j++) {
      int col = n0 + j * 16 + l15;
      float bias = by[col];
      for (int e = 0; e < 4; e++) {
        int row = m0 + i * 16 + q * 4 + e;   // row = t*128 + b
        int t = row >> 7, b = row & 127;
        out[((size_t)b * SEQ_T + t) * VOC + col] = acc[i][j][e] + bias;
      }
    }
}

__global__ void finals(const f16* __restrict__ h0, const f16* __restrict__ h1,
                       float* __restrict__ out) {
  int i = blockIdx.x * 256 + threadIdx.x;  // 131072 threads
  out[(size_t)67108864 + i] = (float)h0[i];
  out[(size_t)67108864 + 131072 + i] = (float)h1[i];
}

extern "C" void kernel_launch(void* const* d_in, const int* in_sizes, int n_in,
                              void* d_out, int out_size, void* d_ws, size_t ws_size,
                              hipStream_t stream) {
  const int*   ids  = (const int*)d_in[0];
  const float* emb  = (const float*)d_in[1];
  const float* wxh0 = (const float*)d_in[2];
  const float* whh0 = (const float*)d_in[3];
  const float* bh0  = (const float*)d_in[4];
  const float* wxh1 = (const float*)d_in[5];
  const float* whh1 = (const float*)d_in[6];
  const float* bh1  = (const float*)d_in[7];
  const float* why  = (const float*)d_in[8];
  const float* by   = (const float*)d_in[9];
  float* out = (float*)d_out;

  char* ws = (char*)d_ws;
  f16* embh   = (f16*)(ws + 0);           // 512*512*2   = 524288
  f16* wxh0h  = (f16*)(ws + 524288);      // 1024*512*2  = 1048576
  f16* whyh   = (f16*)(ws + 1572864);     // 512*1024*2  = 1048576
  f16* h0buf  = (f16*)(ws + 2621440);     // 2 x 262144B = 524288
  f16* h1buf  = (f16*)(ws + 3145728);     // 524288
  unsigned* cnt = (unsigned*)(ws + 3670016);  // 4096
  f16* X0     = (f16*)(ws + 4194304);     // 268435456
  f16* H1     = (f16*)(ws + 272629760);   // 268435456   total ~528 MB

  cvt_f32_f16<<<1024, 256, 0, stream>>>(emb,  embh,  262144);
  cvt_f32_f16<<<2048, 256, 0, stream>>>(wxh0, wxh0h, 524288);
  cvt_f32_f16<<<2048, 256, 0, stream>>>(why,  whyh,  524288);
  hipMemsetAsync(ws + 2621440, 0, 1052672, stream);  // h0buf + h1buf + cnt

  phaseA<<<32768, 256, 0, stream>>>(ids, embh, wxh0h, bh0, X0);

  rnn_persist<<<128, 256, 0, stream>>>(whh0, wxh1, whh1, bh1,
                                       X0, h0buf, h1buf, H1, cnt);

  logitsK<<<16384, 256, 0, stream>>>(H1, whyh, by, out);
  finals<<<512, 256, 0, stream>>>(h0buf, h1buf, out);
}

// Round 4
// 9643.313 us; speedup vs baseline: 2.7148x; 1.0330x over previous
//
#include <hip/hip_runtime.h>

#define SEQ_T 1024
#define HID   1024
#define EMB   512
#define VOC   512

typedef _Float16 f16;
typedef _Float16 half8 __attribute__((ext_vector_type(8)));
typedef float floatx4 __attribute__((ext_vector_type(4)));

__device__ __forceinline__ float tanh_fast(float x) {
  float e = __expf(2.0f * x);
  return 1.0f - 2.0f / (e + 1.0f);
}

// Cache-bypassing (coherence-point) load/store: data moves through the
// Infinity Cache directly, so no buffer_inv / buffer_wbl2 fences are needed
// for cross-XCD visibility.
__device__ __forceinline__ half8 ld_cc(const f16* p) {
  half8 v;
  asm volatile("global_load_dwordx4 %0, %1, off sc0 sc1"
               : "=v"(v) : "v"(p) : "memory");
  return v;
}
__device__ __forceinline__ void st_cc(f16* p, f16 x) {
  unsigned v = (unsigned)__builtin_bit_cast(unsigned short, x);
  asm volatile("global_store_short %0, %1, off sc0 sc1"
               :: "v"(p), "v"(v) : "memory");
}
__device__ __forceinline__ void st_flag(unsigned* p, unsigned v) {
  asm volatile("global_store_dword %0, %1, off sc0 sc1"
               :: "v"(p), "v"(v) : "memory");
}
#define VMCNT(n) asm volatile("s_waitcnt vmcnt(" #n ")" ::: "memory")

// Combined dual spin: wait until all 64 A-flags >= ta AND all 64 B-flags >= tb.
// Lane l polls slot l of each array (64 distinct cachelines, ONE wave
// instruction per array, both loads in flight -> one IC round-trip per poll).
__device__ __forceinline__ void spin_flags(const unsigned* pA, const unsigned* pB,
                                           unsigned ta, unsigned tb) {
  for (;;) {
    unsigned a, b;
    asm volatile("global_load_dword %0, %2, off sc0 sc1\n\t"
                 "global_load_dword %1, %3, off sc0 sc1\n\t"
                 "s_waitcnt vmcnt(0)"
                 : "=&v"(a), "=&v"(b) : "v"(pA), "v"(pB) : "memory");
    if (__ballot((a >= ta) && (b >= tb)) == ~0ull) return;
    __builtin_amdgcn_s_sleep(1);
  }
}

__global__ void cvt_f32_f16(const float* __restrict__ src, f16* __restrict__ dst, int n) {
  int i = blockIdx.x * 256 + threadIdx.x;
  if (i < n) dst[i] = (f16)src[i];
}

// X0[(t*128+b)][j] = sum_k emb[ids[b][t]][k] * wxh0[j][k] + b_h0[j]   (store f16)
__global__ __launch_bounds__(256) void phaseA(
    const int* __restrict__ ids, const f16* __restrict__ embh,
    const f16* __restrict__ wxh0h, const float* __restrict__ bh0,
    f16* __restrict__ X0)
{
  int bx = blockIdx.x;
  int mt = bx >> 4, nt = bx & 15;
  int wave = threadIdx.x >> 6, lane = threadIdx.x & 63;
  int m0 = mt * 64 + (wave & 1) * 32;
  int n0 = nt * 64 + (wave >> 1) * 32;
  int l15 = lane & 15, q = lane >> 4;

  int mA = m0 + l15, mB = mA + 16;
  const f16* a0p = embh + (size_t)ids[(mA & 127) * SEQ_T + (mA >> 7)] * EMB + q * 8;
  const f16* a1p = embh + (size_t)ids[(mB & 127) * SEQ_T + (mB >> 7)] * EMB + q * 8;
  const f16* b0p = wxh0h + (size_t)(n0 + l15) * EMB + q * 8;
  const f16* b1p = wxh0h + (size_t)(n0 + 16 + l15) * EMB + q * 8;

  floatx4 acc[2][2] = {};
  for (int k = 0; k < EMB; k += 32) {
    half8 a0 = *(const half8*)(a0p + k);
    half8 a1 = *(const half8*)(a1p + k);
    half8 b0 = *(const half8*)(b0p + k);
    half8 b1 = *(const half8*)(b1p + k);
    acc[0][0] = __builtin_amdgcn_mfma_f32_16x16x32_f16(a0, b0, acc[0][0], 0, 0, 0);
    acc[0][1] = __builtin_amdgcn_mfma_f32_16x16x32_f16(a0, b1, acc[0][1], 0, 0, 0);
    acc[1][0] = __builtin_amdgcn_mfma_f32_16x16x32_f16(a1, b0, acc[1][0], 0, 0, 0);
    acc[1][1] = __builtin_amdgcn_mfma_f32_16x16x32_f16(a1, b1, acc[1][1], 0, 0, 0);
  }
  for (int i = 0; i < 2; i++)
    for (int j = 0; j < 2; j++) {
      int col = n0 + j * 16 + l15;
      float bias = bh0[col];
      for (int e = 0; e < 4; e++) {
        int row = m0 + i * 16 + q * 4 + e;
        X0[(size_t)row * HID + col] = (f16)(acc[i][j][e] + bias);
      }
    }
}

// Persistent recurrence kernel: 128 WGs (8 row-blocks x 16 col-blocks),
// each WG computes BOTH layers for its (r,c) tile; layer 1 lags one step.
// Per iteration t (0..1024):
//   combined single-round-trip poll on {A-flags >= t, B-flags >= t-1}
//   gather {h0(t-1), h1(t-2)} row-slices into LDS  [ONE cross-WG data hop]
//   A-part (t<1024): h0(t) = tanh(X0(t) + h0(t-1)@Whh0^T)
//   B-part (t>=1):   h1(t-1) = tanh(h0(t-1)@Wxh1^T + h1(t-2)@Whh1^T + b)
// Release protocol: per-WAVE private flag words (64B apart), plain sc0sc1
// dword stores of the step number -> NO atomic RMW serialization (was 128
// serialized same-line atomics per row per step). A-flag post's vmcnt(0)
// (h0 store acks) is placed AFTER the B MFMAs so the ack round-trip hides
// under compute. B-flag(t) is posted after gather(t) reads -> still guards
// h0buf/h1buf reuse by writers at t+1.
__global__ __launch_bounds__(256, 1) void rnn_persist(
    const float* __restrict__ whh0, const float* __restrict__ wxh1,
    const float* __restrict__ whh1, const float* __restrict__ bh1,
    const f16* __restrict__ X0, f16* __restrict__ h0buf, f16* __restrict__ h1buf,
    f16* __restrict__ H1, unsigned* __restrict__ flags)
{
  __shared__ half8 lds[4096];   // [0,2048): h0(t-1) stage; [2048,4096): h1(t-2) stage

  const int wg = blockIdx.x;       // 0..127
  const int r = wg >> 4;           // row-block 0..7 (16 batch rows each)
  const int c = wg & 15;           // col-block 0..15 (64 cols each)
  const int wave = threadIdx.x >> 6;
  const int lane = threadIdx.x & 63;
  const int l15 = lane & 15, q = lane >> 4;
  const int r0 = r * 16;
  const int col = c * 64 + wave * 16 + l15;

  // Flag layout: slot = 16 uints (64B). Row r: 64 slots (16 WGs x 4 waves).
  // A-flags at [0, 8192) uints; B-flags at [8192, 16384) uints.
  unsigned* fA = flags + r * 1024;
  unsigned* fB = flags + 8192 + r * 1024;
  unsigned* myA = fA + (c * 4 + wave) * 16;
  unsigned* myB = fB + (c * 4 + wave) * 16;
  const unsigned* pollA = fA + lane * 16;
  const unsigned* pollB = fB + lane * 16;

  // ---- weights: Whh0 | Wxh1 | Whh1 for this col, 96 frags ----
  half8 wa[32], wbx[32], wbh[32];
  {
    const float* w0 = whh0 + (size_t)col * HID + q * 8;
    const float* w1 = wxh1 + (size_t)col * HID + q * 8;
    const float* w2 = whh1 + (size_t)col * HID + q * 8;
    #pragma unroll
    for (int i = 0; i < 32; i++) {
      const float* p0 = w0 + i * 32;
      const float* p1 = w1 + i * 32;
      const float* p2 = w2 + i * 32;
      #pragma unroll
      for (int j = 0; j < 8; j++) {
        wa[i][j]  = (f16)p0[j];
        wbx[i][j] = (f16)p1[j];
        wbh[i][j] = (f16)p2[j];
      }
    }
  }
  const float bias1 = bh1[col];

  for (int t = 0; t <= SEQ_T; t++) {
    // h0(s) lives in h0buf[(s+1)&1]; h1(s) lives in h1buf[(s+1)&1]
    const f16* h0prev  = h0buf + (size_t)(t & 1) * 131072;        // h0(t-1)
    f16*       h0next  = h0buf + (size_t)((t + 1) & 1) * 131072;  // h0(t)
    const f16* h1prev2 = h1buf + (size_t)((t + 1) & 1) * 131072;  // h1(t-2)
    f16*       h1new   = h1buf + (size_t)(t & 1) * 131072;        // h1(t-1)

    // X0 prefetch (independent of sync) before the spin
    f16 xv[4];
    if (t < SEQ_T) {
      const f16* x0t = X0 + (size_t)t * 131072;
      #pragma unroll
      for (int e = 0; e < 4; e++)
        xv[e] = x0t[(size_t)(r0 + q * 4 + e) * HID + col];
    }

    // detect: one combined poll (A(t-1) complete AND B of iter t-1 complete)
    if (t >= 1)
      spin_flags(pollA, pollB, (unsigned)t, (unsigned)(t >= 2 ? t - 1 : 0));

    // gather: this wave loads h0 frags 8w..8w+7 and h1 frags 8w..8w+7
    const f16* ap0 = h0prev  + (size_t)(r0 + l15) * HID + q * 8;
    const f16* ap1 = h1prev2 + (size_t)(r0 + l15) * HID + q * 8;
    half8 v0[8], v1[8];
    #pragma unroll
    for (int i = 0; i < 8; i++) v0[i] = ld_cc(ap0 + (8 * wave + i) * 32);
    #pragma unroll
    for (int i = 0; i < 8; i++) v1[i] = ld_cc(ap1 + (8 * wave + i) * 32);
    VMCNT(8);     // v0 batch (and xv prefetch) landed
    #pragma unroll
    for (int i = 0; i < 8; i++) lds[(8 * wave + i) * 64 + lane] = v0[i];
    VMCNT(0);     // v1 batch landed
    #pragma unroll
    for (int i = 0; i < 8; i++) lds[2048 + (8 * wave + i) * 64 + lane] = v1[i];
    __syncthreads();

    // ---- A-part: h0(t) = tanh(X0(t) + h0(t-1) @ Whh0^T) ----
    if (t < SEQ_T) {
      floatx4 a0 = {}, a1 = {};
      #pragma unroll
      for (int i = 0; i < 16; i++) {
        half8 f0 = lds[i * 64 + lane];
        half8 f1 = lds[(16 + i) * 64 + lane];
        a0 = __builtin_amdgcn_mfma_f32_16x16x32_f16(f0, wa[i],      a0, 0, 0, 0);
        a1 = __builtin_amdgcn_mfma_f32_16x16x32_f16(f1, wa[16 + i], a1, 0, 0, 0);
      }
      #pragma unroll
      for (int e = 0; e < 4; e++) {
        int row = r0 + q * 4 + e;
        float vv = a0[e] + a1[e] + (float)xv[e];
        st_cc(h0next + (size_t)row * HID + col, (f16)tanh_fast(vv));
      }
    }

    // ---- B-part MFMAs (overlap the h0 store-ack drain under these) ----
    floatx4 b0 = {}, b1 = {};
    if (t >= 1) {
      #pragma unroll
      for (int i = 0; i < 32; i++) {
        half8 f0 = lds[i * 64 + lane];          // h0(t-1)
        half8 f1 = lds[2048 + i * 64 + lane];   // h1(t-2)
        b0 = __builtin_amdgcn_mfma_f32_16x16x32_f16(f0, wbx[i], b0, 0, 0, 0);
        b1 = __builtin_amdgcn_mfma_f32_16x16x32_f16(f1, wbh[i], b1, 0, 0, 0);
      }
    }

    // release A: h0 stores are the only outstanding VMEM; acks likely
    // already back (drain overlapped with B MFMAs above)
    if (t < SEQ_T) {
      VMCNT(0);
      if (lane == 0) st_flag(myA, (unsigned)(t + 1));
    }

    // ---- B-part epilogue: h1(t-1) = tanh(...), store, release B ----
    if (t >= 1) {
      f16 hv[4];
      #pragma unroll
      for (int e = 0; e < 4; e++) {
        int row = r0 + q * 4 + e;
        hv[e] = (f16)tanh_fast(b0[e] + b1[e] + bias1);
        st_cc(h1new + (size_t)row * HID + col, hv[e]);
      }
      VMCNT(0);   // h1 write-through acks
      if (lane == 0) st_flag(myB, (unsigned)t);
      // output slice t-1: cached stores issued AFTER the post (off critical path)
      f16* h1t = H1 + (size_t)(t - 1) * 131072;
      #pragma unroll
      for (int e = 0; e < 4; e++) {
        int row = r0 + q * 4 + e;
        h1t[(size_t)row * HID + col] = hv[e];
      }
    }
    __syncthreads();   // protect LDS reuse before next iteration's gather-writes
  }
}

// logits[b][t][v] = sum_k H1[(t*128+b)][k]*why[v][k] + by[v]   (fp32 out)
__global__ __launch_bounds__(256) void logitsK(
    const f16* __restrict__ H1, const f16* __restrict__ whyh,
    const float* __restrict__ by, float* __restrict__ out)
{
  int bx = blockIdx.x;
  int mt = bx >> 3, nt = bx & 7;
  int wave = threadIdx.x >> 6, lane = threadIdx.x & 63;
  int m0 = mt * 64 + (wave & 1) * 32;
  int n0 = nt * 64 + (wave >> 1) * 32;
  int l15 = lane & 15, q = lane >> 4;

  const f16* a0p = H1 + (size_t)(m0 + l15) * HID + q * 8;
  const f16* a1p = H1 + (size_t)(m0 + 16 + l15) * HID + q * 8;
  const f16* b0p = whyh + (size_t)(n0 + l15) * HID + q * 8;
  const f16* b1p = whyh + (size_t)(n0 + 16 + l15) * HID + q * 8;

  floatx4 acc[2][2] = {};
  for (int k = 0; k < HID; k += 32) {
    half8 a0 = *(const half8*)(a0p + k);
    half8 a1 = *(const half8*)(a1p + k);
    half8 b0 = *(const half8*)(b0p + k);
    half8 b1 = *(const half8*)(b1p + k);
    acc[0][0] = __builtin_amdgcn_mfma_f32_16x16x32_f16(a0, b0, acc[0][0], 0, 0, 0);
    acc[0][1] = __builtin_amdgcn_mfma_f32_16x16x32_f16(a0, b1, acc[0][1], 0, 0, 0);
    acc[1][0] = __builtin_amdgcn_mfma_f32_16x16x32_f16(a1, b0, acc[1][0], 0, 0, 0);
    acc[1][1] = __builtin_amdgcn_mfma_f32_16x16x32_f16(a1, b1, acc[1][1], 0, 0, 0);
  }
  for (int i = 0; i < 2; i++)
    for (int j = 0; j < 2; j++) {
      int col = n0 + j * 16 + l15;
      float bias = by[col];
      for (int e = 0; e < 4; e++) {
        int row = m0 + i * 16 + q * 4 + e;   // row = t*128 + b
        int t = row >> 7, b = row & 127;
        out[((size_t)b * SEQ_T + t) * VOC + col] = acc[i][j][e] + bias;
      }
    }
}

__global__ void finals(const f16* __restrict__ h0, const f16* __restrict__ h1,
                       float* __restrict__ out) {
  int i = blockIdx.x * 256 + threadIdx.x;  // 131072 threads
  out[(size_t)67108864 + i] = (float)h0[i];
  out[(size_t)67108864 + 131072 + i] = (float)h1[i];
}

extern "C" void kernel_launch(void* const* d_in, const int* in_sizes, int n_in,
                              void* d_out, int out_size, void* d_ws, size_t ws_size,
                              hipStream_t stream) {
  const int*   ids  = (const int*)d_in[0];
  const float* emb  = (const float*)d_in[1];
  const float* wxh0 = (const float*)d_in[2];
  const float* whh0 = (const float*)d_in[3];
  const float* bh0  = (const float*)d_in[4];
  const float* wxh1 = (const float*)d_in[5];
  const float* whh1 = (const float*)d_in[6];
  const float* bh1  = (const float*)d_in[7];
  const float* why  = (const float*)d_in[8];
  const float* by   = (const float*)d_in[9];
  float* out = (float*)d_out;

  char* ws = (char*)d_ws;
  f16* embh   = (f16*)(ws + 0);           // 512*512*2   = 524288
  f16* wxh0h  = (f16*)(ws + 524288);      // 1024*512*2  = 1048576
  f16* whyh   = (f16*)(ws + 1572864);     // 512*1024*2  = 1048576
  f16* h0buf  = (f16*)(ws + 2621440);     // 2 x 262144B = 524288
  f16* h1buf  = (f16*)(ws + 3145728);     // 524288
  unsigned* flags = (unsigned*)(ws + 3670016);  // 2*8*64*64B = 65536
  f16* X0     = (f16*)(ws + 4194304);     // 268435456
  f16* H1     = (f16*)(ws + 272629760);   // 268435456   total ~528 MB

  cvt_f32_f16<<<1024, 256, 0, stream>>>(emb,  embh,  262144);
  cvt_f32_f16<<<2048, 256, 0, stream>>>(wxh0, wxh0h, 524288);
  cvt_f32_f16<<<2048, 256, 0, stream>>>(why,  whyh,  524288);
  hipMemsetAsync(ws + 2621440, 0, 1114112, stream);  // h0buf + h1buf + flags

  phaseA<<<32768, 256, 0, stream>>>(ids, embh, wxh0h, bh0, X0);

  rnn_persist<<<128, 256, 0, stream>>>(whh0, wxh1, whh1, bh1,
                                       X0, h0buf, h1buf, H1, flags);

  logitsK<<<16384, 256, 0, stream>>>(H1, whyh, by, out);
  finals<<<512, 256, 0, stream>>>(h0buf, h1buf, out);
}

// Round 6
// 8144.113 us; speedup vs baseline: 3.2145x; 1.1841x over previous
//
#include <hip/hip_runtime.h>

#define SEQ_T 1024
#define HID   1024
#define EMB   512
#define VOC   512

typedef _Float16 f16;
typedef _Float16 half8 __attribute__((ext_vector_type(8)));
typedef float floatx4 __attribute__((ext_vector_type(4)));

__device__ __forceinline__ float tanh_fast(float x) {
  float e = __expf(2.0f * x);
  return 1.0f - 2.0f / (e + 1.0f);
}

// sc0 sc1: write-through / read at the coherence point (IC) - cross-XCD safe.
// sc0 only (loads): L1-bypass, L2-CACHEABLE - used for the gather AFTER an
// agent acquire fence (buffer_inv) so same-XCD WGs share one IC fetch/line.
__device__ __forceinline__ half8 ld_l2(const f16* p) {
  half8 v;
  asm volatile("global_load_dwordx4 %0, %1, off sc0"
               : "=v"(v) : "v"(p) : "memory");
  return v;
}
__device__ __forceinline__ void st_cc(f16* p, f16 x) {
  unsigned v = (unsigned)__builtin_bit_cast(unsigned short, x);
  asm volatile("global_store_short %0, %1, off sc0 sc1"
               :: "v"(p), "v"(v) : "memory");
}
__device__ __forceinline__ void st_flag(unsigned* p, unsigned v) {
  asm volatile("global_store_dword %0, %1, off sc0 sc1"
               :: "v"(p), "v"(v) : "memory");
}
#define VMCNT(n) asm volatile("s_waitcnt vmcnt(" #n ")" ::: "memory")

// Row-step poll: 16 WG-flags per row, lane l polls slot (l&15) (16 distinct
// cachelines, wave-coalesced; IC-truth via sc0sc1). One RT per round.
__device__ __forceinline__ void spin_row(const unsigned* p, unsigned tgt) {
  for (;;) {
    unsigned v;
    asm volatile("global_load_dword %0, %1, off sc0 sc1\n\t"
                 "s_waitcnt vmcnt(0)"
                 : "=v"(v) : "v"(p) : "memory");
    if (__ballot(v >= tgt) == ~0ull) return;
    __builtin_amdgcn_s_sleep(2);
  }
}

__global__ void cvt_f32_f16(const float* __restrict__ src, f16* __restrict__ dst, int n) {
  int i = blockIdx.x * 256 + threadIdx.x;
  if (i < n) dst[i] = (f16)src[i];
}

// X0[(t*128+b)][j] = sum_k emb[ids[b][t]][k] * wxh0[j][k] + b_h0[j]   (store f16)
__global__ __launch_bounds__(256) void phaseA(
    const int* __restrict__ ids, const f16* __restrict__ embh,
    const f16* __restrict__ wxh0h, const float* __restrict__ bh0,
    f16* __restrict__ X0)
{
  int bx = blockIdx.x;
  int mt = bx >> 4, nt = bx & 15;
  int wave = threadIdx.x >> 6, lane = threadIdx.x & 63;
  int m0 = mt * 64 + (wave & 1) * 32;
  int n0 = nt * 64 + (wave >> 1) * 32;
  int l15 = lane & 15, q = lane >> 4;

  int mA = m0 + l15, mB = mA + 16;
  const f16* a0p = embh + (size_t)ids[(mA & 127) * SEQ_T + (mA >> 7)] * EMB + q * 8;
  const f16* a1p = embh + (size_t)ids[(mB & 127) * SEQ_T + (mB >> 7)] * EMB + q * 8;
  const f16* b0p = wxh0h + (size_t)(n0 + l15) * EMB + q * 8;
  const f16* b1p = wxh0h + (size_t)(n0 + 16 + l15) * EMB + q * 8;

  floatx4 acc[2][2] = {};
  for (int k = 0; k < EMB; k += 32) {
    half8 a0 = *(const half8*)(a0p + k);
    half8 a1 = *(const half8*)(a1p + k);
    half8 b0 = *(const half8*)(b0p + k);
    half8 b1 = *(const half8*)(b1p + k);
    acc[0][0] = __builtin_amdgcn_mfma_f32_16x16x32_f16(a0, b0, acc[0][0], 0, 0, 0);
    acc[0][1] = __builtin_amdgcn_mfma_f32_16x16x32_f16(a0, b1, acc[0][1], 0, 0, 0);
    acc[1][0] = __builtin_amdgcn_mfma_f32_16x16x32_f16(a1, b0, acc[1][0], 0, 0, 0);
    acc[1][1] = __builtin_amdgcn_mfma_f32_16x16x32_f16(a1, b1, acc[1][1], 0, 0, 0);
  }
  for (int i = 0; i < 2; i++)
    for (int j = 0; j < 2; j++) {
      int col = n0 + j * 16 + l15;
      float bias = bh0[col];
      for (int e = 0; e < 4; e++) {
        int row = m0 + i * 16 + q * 4 + e;
        X0[(size_t)row * HID + col] = (f16)(acc[i][j][e] + bias);
      }
    }
}

// Persistent recurrence: 128 WGs (8 row-blocks x 16 col-blocks), both layers
// per WG, layer 1 lagged one step. Per iteration t (0..1024):
//   poll: 16 WG-flags of row r >= t  ("iteration t-1 fully done")
//   agent acquire fence (buffer_inv) -> sc0 L2-cacheable gather is fresh
//   gather {h0(t-1), h1(t-2)} into LDS (one cross-WG data hop, L2-deduped)
//   fused loop: A-MFMAs + B(Wxh1)-MFMAs share each h0 fragment (1 ds_read)
//   A store h0(t) [t<1024]  ->  B(Whh1) loop  ->  B store h1(t-1) [t>=1]
//   ONE vmcnt(0) drain + syncthreads + thread0 posts flag = t+1
//   H1 cached stores after the post (off the critical chain)
// Liveness never depends on placement; all exchange stores are write-through
// to the IC (no dirty L2 lines -> no cross-launch corruption).
__global__ __launch_bounds__(256, 1) void rnn_persist(
    const float* __restrict__ whh0, const float* __restrict__ wxh1,
    const float* __restrict__ whh1, const float* __restrict__ bh1,
    const f16* __restrict__ X0, f16* __restrict__ h0buf, f16* __restrict__ h1buf,
    f16* __restrict__ H1, unsigned* __restrict__ flags)
{
  __shared__ half8 lds[4096];   // [0,2048): h0(t-1); [2048,4096): h1(t-2)

  const int wg = blockIdx.x;       // 0..127
  const int r = wg >> 4;           // row-block 0..7 (16 batch rows each)
  const int c = wg & 15;           // col-block 0..15 (64 cols each)
  const int wave = threadIdx.x >> 6;
  const int lane = threadIdx.x & 63;
  const int l15 = lane & 15, q = lane >> 4;
  const int r0 = r * 16;
  const int col = c * 64 + wave * 16 + l15;

  // Flags: row r has 16 slots (one per WG), 64B apart.
  unsigned* myflag = flags + r * 256 + c * 16;
  const unsigned* pollp = flags + r * 256 + (lane & 15) * 16;

  // ---- weights: Whh0 | Wxh1 | Whh1 for this col, 96 frags ----
  half8 wa[32], wbx[32], wbh[32];
  {
    const float* w0 = whh0 + (size_t)col * HID + q * 8;
    const float* w1 = wxh1 + (size_t)col * HID + q * 8;
    const float* w2 = whh1 + (size_t)col * HID + q * 8;
    #pragma unroll
    for (int i = 0; i < 32; i++) {
      const float* p0 = w0 + i * 32;
      const float* p1 = w1 + i * 32;
      const float* p2 = w2 + i * 32;
      #pragma unroll
      for (int j = 0; j < 8; j++) {
        wa[i][j]  = (f16)p0[j];
        wbx[i][j] = (f16)p1[j];
        wbh[i][j] = (f16)p2[j];
      }
    }
  }
  const float bias1 = bh1[col];

  for (int t = 0; t <= SEQ_T; t++) {
    const f16* h0prev  = h0buf + (size_t)(t & 1) * 131072;        // h0(t-1)
    f16*       h0next  = h0buf + (size_t)((t + 1) & 1) * 131072;  // h0(t)
    const f16* h1prev2 = h1buf + (size_t)((t + 1) & 1) * 131072;  // h1(t-2)
    f16*       h1new   = h1buf + (size_t)(t & 1) * 131072;        // h1(t-1)

    // X0 prefetch (independent of sync) before the spin
    f16 xv[4];
    if (t < SEQ_T) {
      const f16* x0t = X0 + (size_t)t * 131072;
      #pragma unroll
      for (int e = 0; e < 4; e++)
        xv[e] = x0t[(size_t)(r0 + q * 4 + e) * HID + col];
    }

    // detect: iteration t-1 fully done across the row (single flag array)
    if (t >= 1) spin_row(pollp, (unsigned)t);

    // acquire: invalidate caches so the sc0 (L2-cacheable) gather is fresh.
    // Also covers cross-launch staleness at t=0.
    __builtin_amdgcn_fence(__ATOMIC_ACQUIRE, "agent");

    // gather: this wave loads h0 frags 8w..8w+7 and h1 frags 8w..8w+7
    const f16* ap0 = h0prev  + (size_t)(r0 + l15) * HID + q * 8;
    const f16* ap1 = h1prev2 + (size_t)(r0 + l15) * HID + q * 8;
    half8 v0[8], v1[8];
    #pragma unroll
    for (int i = 0; i < 8; i++) v0[i] = ld_l2(ap0 + (8 * wave + i) * 32);
    #pragma unroll
    for (int i = 0; i < 8; i++) v1[i] = ld_l2(ap1 + (8 * wave + i) * 32);
    VMCNT(8);
    #pragma unroll
    for (int i = 0; i < 8; i++) lds[(8 * wave + i) * 64 + lane] = v0[i];
    VMCNT(0);
    #pragma unroll
    for (int i = 0; i < 8; i++) lds[2048 + (8 * wave + i) * 64 + lane] = v1[i];
    __syncthreads();

    // ---- fused loop: each h0 fragment feeds A (Whh0) and B (Wxh1) ----
    floatx4 a0 = {}, a1 = {}, bx0 = {}, bx1 = {};
    #pragma unroll
    for (int i = 0; i < 16; i++) {
      half8 f0 = lds[(2 * i) * 64 + lane];
      half8 f1 = lds[(2 * i + 1) * 64 + lane];
      a0  = __builtin_amdgcn_mfma_f32_16x16x32_f16(f0, wa[2 * i],      a0,  0, 0, 0);
      a1  = __builtin_amdgcn_mfma_f32_16x16x32_f16(f1, wa[2 * i + 1],  a1,  0, 0, 0);
      bx0 = __builtin_amdgcn_mfma_f32_16x16x32_f16(f0, wbx[2 * i],     bx0, 0, 0, 0);
      bx1 = __builtin_amdgcn_mfma_f32_16x16x32_f16(f1, wbx[2 * i + 1], bx1, 0, 0, 0);
    }

    // A epilogue: h0(t) = tanh(X0(t) + h0(t-1)@Whh0^T)  (stores fly under B)
    if (t < SEQ_T) {
      #pragma unroll
      for (int e = 0; e < 4; e++) {
        int row = r0 + q * 4 + e;
        float vv = a0[e] + a1[e] + (float)xv[e];
        st_cc(h0next + (size_t)row * HID + col, (f16)tanh_fast(vv));
      }
    }

    // ---- B second half: h1(t-2) @ Whh1^T ----
    floatx4 bh0a = {}, bh1a = {};
    #pragma unroll
    for (int i = 0; i < 16; i++) {
      half8 g0 = lds[2048 + (2 * i) * 64 + lane];
      half8 g1 = lds[2048 + (2 * i + 1) * 64 + lane];
      bh0a = __builtin_amdgcn_mfma_f32_16x16x32_f16(g0, wbh[2 * i],     bh0a, 0, 0, 0);
      bh1a = __builtin_amdgcn_mfma_f32_16x16x32_f16(g1, wbh[2 * i + 1], bh1a, 0, 0, 0);
    }

    // B epilogue: h1(t-1) = tanh(...)
    f16 hv[4];
    if (t >= 1) {
      #pragma unroll
      for (int e = 0; e < 4; e++) {
        int row = r0 + q * 4 + e;
        hv[e] = (f16)tanh_fast(bx0[e] + bx1[e] + bh0a[e] + bh1a[e] + bias1);
        st_cc(h1new + (size_t)row * HID + col, hv[e]);
      }
    }

    // single release: drain A+B exchange stores, then one flag per WG
    VMCNT(0);
    __syncthreads();
    if (threadIdx.x == 0) st_flag(myflag, (unsigned)(t + 1));

    // output slice t-1: cached stores after the post (off critical chain)
    if (t >= 1) {
      f16* h1t = H1 + (size_t)(t - 1) * 131072;
      #pragma unroll
      for (int e = 0; e < 4; e++) {
        int row = r0 + q * 4 + e;
        h1t[(size_t)row * HID + col] = hv[e];
      }
    }
  }
}

// logits[b][t][v] = sum_k H1[(t*128+b)][k]*why[v][k] + by[v]   (fp32 out)
__global__ __launch_bounds__(256) void logitsK(
    const f16* __restrict__ H1, const f16* __restrict__ whyh,
    const float* __restrict__ by, float* __restrict__ out)
{
  int bx = blockIdx.x;
  int mt = bx >> 3, nt = bx & 7;
  int wave = threadIdx.x >> 6, lane = threadIdx.x & 63;
  int m0 = mt * 64 + (wave & 1) * 32;
  int n0 = nt * 64 + (wave >> 1) * 32;
  int l15 = lane & 15, q = lane >> 4;

  const f16* a0p = H1 + (size_t)(m0 + l15) * HID + q * 8;
  const f16* a1p = H1 + (size_t)(m0 + 16 + l15) * HID + q * 8;
  const f16* b0p = whyh + (size_t)(n0 + l15) * HID + q * 8;
  const f16* b1p = whyh + (size_t)(n0 + 16 + l15) * HID + q * 8;

  floatx4 acc[2][2] = {};
  for (int k = 0; k < HID; k += 32) {
    half8 a0 = *(const half8*)(a0p + k);
    half8 a1 = *(const half8*)(a1p + k);
    half8 b0 = *(const half8*)(b0p + k);
    half8 b1 = *(const half8*)(b1p + k);
    acc[0][0] = __builtin_amdgcn_mfma_f32_16x16x32_f16(a0, b0, acc[0][0], 0, 0, 0);
    acc[0][1] = __builtin_amdgcn_mfma_f32_16x16x32_f16(a0, b1, acc[0][1], 0, 0, 0);
    acc[1][0] = __builtin_amdgcn_mfma_f32_16x16x32_f16(a1, b0, acc[1][0], 0, 0, 0);
    acc[1][1] = __builtin_amdgcn_mfma_f32_16x16x32_f16(a1, b1, acc[1][1], 0, 0, 0);
  }
  for (int i = 0; i < 2; i++)
    for (int j = 0; j < 2; j++) {
      int col = n0 + j * 16 + l15;
      float bias = by[col];
      for (int e = 0; e < 4; e++) {
        int row = m0 + i * 16 + q * 4 + e;   // row = t*128 + b
        int t = row >> 7, b = row & 127;
        out[((size_t)b * SEQ_T + t) * VOC + col] = acc[i][j][e] + bias;
      }
    }
}

__global__ void finals(const f16* __restrict__ h0, const f16* __restrict__ h1,
                       float* __restrict__ out) {
  int i = blockIdx.x * 256 + threadIdx.x;  // 131072 threads
  out[(size_t)67108864 + i] = (float)h0[i];
  out[(size_t)67108864 + 131072 + i] = (float)h1[i];
}

extern "C" void kernel_launch(void* const* d_in, const int* in_sizes, int n_in,
                              void* d_out, int out_size, void* d_ws, size_t ws_size,
                              hipStream_t stream) {
  const int*   ids  = (const int*)d_in[0];
  const float* emb  = (const float*)d_in[1];
  const float* wxh0 = (const float*)d_in[2];
  const float* whh0 = (const float*)d_in[3];
  const float* bh0  = (const float*)d_in[4];
  const float* wxh1 = (const float*)d_in[5];
  const float* whh1 = (const float*)d_in[6];
  const float* bh1  = (const float*)d_in[7];
  const float* why  = (const float*)d_in[8];
  const float* by   = (const float*)d_in[9];
  float* out = (float*)d_out;

  char* ws = (char*)d_ws;
  f16* embh   = (f16*)(ws + 0);           // 512*512*2   = 524288
  f16* wxh0h  = (f16*)(ws + 524288);      // 1024*512*2  = 1048576
  f16* whyh   = (f16*)(ws + 1572864);     // 512*1024*2  = 1048576
  f16* h0buf  = (f16*)(ws + 2621440);     // 2 x 262144B = 524288
  f16* h1buf  = (f16*)(ws + 3145728);     // 524288
  unsigned* flags = (unsigned*)(ws + 3670016);  // 8 rows * 16 WGs * 64B = 8KB
  f16* X0     = (f16*)(ws + 4194304);     // 268435456
  f16* H1     = (f16*)(ws + 272629760);   // 268435456   total ~528 MB

  cvt_f32_f16<<<1024, 256, 0, stream>>>(emb,  embh,  262144);
  cvt_f32_f16<<<2048, 256, 0, stream>>>(wxh0, wxh0h, 524288);
  cvt_f32_f16<<<2048, 256, 0, stream>>>(why,  whyh,  524288);
  hipMemsetAsync(ws + 2621440, 0, 1114112, stream);  // h0buf + h1buf + flags

  phaseA<<<32768, 256, 0, stream>>>(ids, embh, wxh0h, bh0, X0);

  rnn_persist<<<128, 256, 0, stream>>>(whh0, wxh1, whh1, bh1,
                                       X0, h0buf, h1buf, H1, flags);

  logitsK<<<16384, 256, 0, stream>>>(H1, whyh, by, out);
  finals<<<512, 256, 0, stream>>>(h0buf, h1buf, out);
}